// Round 5
// baseline (146.348 us; speedup 1.0000x reference)
//
#include <hip/hip_runtime.h>

// Problem constants: B=2, C=32, H=128, W=256, maxdisp=12 -> D=23, shift = di-11
#define BB 2
#define CC 32
#define HH 128
#define WW 256
#define DD 23
#define HW (HH * WW)

#define SEG 64            // pixels per block (W split 4 ways)
#define NSEG 4
#define NCOLS 151         // staged cols: [64s-75 .. 64s+75]
#define SC 36             // col stride in dwords (144 B, 16B-aligned)

// LDS: smem[col*SC + c] = feat_r[b, c, h, col + COL0], zero outside [0,W).
// After compute it is reused as the partial-sum slab: slab[(di*3+j)*64+px],
// j = rank of non-owner wave (3*23*64*4 B = 17664 <= 21744).
//
// R4 lesson (counters): __builtin_nontemporal_store on scattered 4B output
// words defeated L2 write-combining -> WRITE_SIZE 131->233 MB, 7x slowdown.
// Plain stores let L2 assemble full lines. NO nontemporal anywhere.

__global__ __launch_bounds__(256, 4) void cost_volume_kernel(
    const float* __restrict__ feat_l,
    const float* __restrict__ feat_r,
    const float* __restrict__ disp,
    float* __restrict__ out)
{
    __shared__ __align__(16) float smem[NCOLS * SC];   // 21744 B

    const int t  = threadIdx.x;
    const int q  = t >> 6;          // wave id = channel octet (c0 = 8q)
    const int px = t & 63;          // pixel within segment
    const int s  = blockIdx.x >> 8; // grid = NSEG*256; siblings same XCD
    const int bh = blockIdx.x & 255;
    const int b  = bh >> 7;
    const int h  = bh & 127;
    const int w  = s * SEG + px;
    const int COL0 = s * SEG - 75;
    const int c0 = q * 8;

    // ---- stage feat_r window FIRST (starts LDS-fill critical path early) ----
    #pragma unroll
    for (int cc = 0; cc < 3; ++cc) {
        const int col = cc * 64 + px;
        if (col < NCOLS) {
            const int  gcol = col + COL0;
            const bool inr  = (gcol >= 0) && (gcol < WW);
            const int  gc   = min(max(gcol, 0), WW - 1);   // safe address
            #pragma unroll
            for (int qq = 0; qq < 2; ++qq) {
                const int cq = (q + 4 * qq) * 4;           // channel quad base
                const size_t base = ((size_t)(b * CC + cq)) * HW + (size_t)h * WW + gc;
                const float x0 = feat_r[base];
                const float x1 = feat_r[base + HW];
                const float x2 = feat_r[base + 2 * HW];
                const float x3 = feat_r[base + 3 * HW];
                float4 v;
                v.x = inr ? x0 : 0.0f;
                v.y = inr ? x1 : 0.0f;
                v.z = inr ? x2 : 0.0f;
                v.w = inr ? x3 : 0.0f;
                *(float4*)&smem[col * SC + cq] = v;
            }
        }
    }

    // ---- feat_l / disp loads (plain; L2 handles reuse) ----
    float fl[8];
    const size_t lbase = ((size_t)(b * CC + c0)) * HW + (size_t)h * WW + w;
    #pragma unroll
    for (int k = 0; k < 8; ++k) fl[k] = feat_l[lbase + (size_t)k * HW];
    const float d = disp[(size_t)bh * WW + w];

    __syncthreads();

    // ---- per-pixel interp setup (shared across all di) ----
    const float pxf = (float)w - d;
    const float x0f = floorf(pxf);
    const float w1  = pxf - x0f;          // right-neighbor weight
    const float w0  = 1.0f - w1;
    int lb = (int)x0f - COL0 - 11;        // local col of tap j=0
    lb = min(max(lb, 0), NCOLS - 24);     // no-op for disp in [0,64)

    // ---- 24-tap window, prefetch distance 2, 8 channels per thread ----
    float4 Ta[3], Tb[3];
    #define LOADTAP(idx, j) { \
        const float4* p_ = (const float4*)&smem[(lb + (j)) * SC + c0]; \
        Ta[idx] = p_[0]; Tb[idx] = p_[1]; }

    LOADTAP(0, 0)
    LOADTAP(1, 1)

    float acc[DD];
    #pragma unroll
    for (int di = 0; di < DD; ++di) {
        if (di + 2 < 24) LOADTAP((di + 2) % 3, di + 2)
        const float4 A0 = Ta[di % 3],       A1 = Tb[di % 3];
        const float4 B0 = Ta[(di + 1) % 3], B1 = Tb[(di + 1) % 3];
        float sA = 0.0f, sB = 0.0f;
        sA += fabsf(fmaf(w0, A0.x, fmaf(w1, B0.x, -fl[0])));
        sB += fabsf(fmaf(w0, A0.y, fmaf(w1, B0.y, -fl[1])));
        sA += fabsf(fmaf(w0, A0.z, fmaf(w1, B0.z, -fl[2])));
        sB += fabsf(fmaf(w0, A0.w, fmaf(w1, B0.w, -fl[3])));
        sA += fabsf(fmaf(w0, A1.x, fmaf(w1, B1.x, -fl[4])));
        sB += fabsf(fmaf(w0, A1.y, fmaf(w1, B1.y, -fl[5])));
        sA += fabsf(fmaf(w0, A1.z, fmaf(w1, B1.z, -fl[6])));
        sB += fabsf(fmaf(w0, A1.w, fmaf(w1, B1.w, -fl[7])));
        acc[di] = sA + sB;
    }
    #undef LOADTAP

    // ---- balanced 4-way combine: wave q owns di in [6q, 6q+6) (last: 5) ----
    __syncthreads();                      // all tap reads done before overwrite
    #pragma unroll
    for (int di = 0; di < DD; ++di) {
        const int own = (di < 6) ? 0 : (di < 12) ? 1 : (di < 18) ? 2 : 3;
        if (own != q) {
            const int j = q - (q > own ? 1 : 0);          // 0..2
            smem[(di * 3 + j) * 64 + px] = acc[di];       // stride-1: no conflicts
        }
    }
    __syncthreads();
    {
        const int d0 = q * 6;
        #pragma unroll
        for (int k = 0; k < 6; ++k) {
            const int di = d0 + k;
            if (di < DD) {
                const float v = acc[di]
                              + smem[(di * 3 + 0) * 64 + px]
                              + smem[(di * 3 + 1) * 64 + px]
                              + smem[(di * 3 + 2) * 64 + px];
                out[((size_t)(b * DD + di)) * HW + (size_t)h * WW + w] = v;
            }
        }
    }
}

extern "C" void kernel_launch(void* const* d_in, const int* in_sizes, int n_in,
                              void* d_out, int out_size, void* d_ws, size_t ws_size,
                              hipStream_t stream)
{
    const float* feat_l = (const float*)d_in[0];
    const float* feat_r = (const float*)d_in[1];
    const float* disp   = (const float*)d_in[2];
    float* out = (float*)d_out;

    dim3 grid(NSEG * BB * HH);   // 1024 blocks: (wseg, b, h); 4 blocks/CU
    dim3 block(256);             // 4 waves: one channel-octet each
    cost_volume_kernel<<<grid, block, 0, stream>>>(feat_l, feat_r, disp, out);
}

// Round 6
// 78.604 us; speedup vs baseline: 1.8618x; 1.8618x over previous
//
#include <hip/hip_runtime.h>

// Problem constants: B=2, C=32, H=128, W=256, maxdisp=12 -> D=23, shift = di-11
#define BB 2
#define CC 32
#define HH 128
#define WW 256
#define DD 23
#define HW (HH * WW)

#define SEG 64            // pixels per block (W split 4 ways)
#define NSEG 4
#define NCOLS 151         // staged cols: [64s-75 .. 64s+75]  (64 + 87)
#define SC 36             // col stride in dwords (144 B, 16B-aligned, odd quad)
#define RED 23            // combine stride (23 coprime 32 -> conflict-free)

// EXACT revert to the R3 kernel (best measured: bench 77.4 us).
// R4/R5 bundled changes (staging-first order, balanced combine, NT hints)
// regressed the kernel ~27 -> ~96-111 us; reverting to isolate.

__global__ __launch_bounds__(256, 4) void cost_volume_kernel(
    const float* __restrict__ feat_l,
    const float* __restrict__ feat_r,
    const float* __restrict__ disp,
    float* __restrict__ out)
{
    __shared__ __align__(16) float smem[NCOLS * SC];   // 21744 B -> LDS not limiter

    const int t  = threadIdx.x;
    const int q  = t >> 6;          // wave id = channel octet (c0 = 8q)
    const int px = t & 63;          // pixel within segment
    const int s  = blockIdx.x >> 8; // grid = NSEG*256; siblings same XCD (256%8==0)
    const int bh = blockIdx.x & 255;
    const int b  = bh >> 7;
    const int h  = bh & 127;
    const int w  = s * SEG + px;
    const int COL0 = s * SEG - 75;
    const int c0 = q * 8;

    // ---- early independent global loads (overlap staging latency) ----
    float fl[8];
    const size_t lbase = ((size_t)(b * CC + c0)) * HW + (size_t)h * WW + w;
    #pragma unroll
    for (int k = 0; k < 8; ++k) fl[k] = feat_l[lbase + (size_t)k * HW];
    const float d = disp[(size_t)bh * WW + w];

    // ---- stage feat_r window, channel-interleaved, b128 LDS writes ----
    #pragma unroll
    for (int cc = 0; cc < 3; ++cc) {
        const int col = cc * 64 + px;
        if (col < NCOLS) {
            const int  gcol = col + COL0;
            const bool inr  = (gcol >= 0) && (gcol < WW);
            const int  gc   = min(max(gcol, 0), WW - 1);   // safe address
            #pragma unroll
            for (int qq = 0; qq < 2; ++qq) {
                const int cq = (q + 4 * qq) * 4;           // channel quad base
                const size_t base = ((size_t)(b * CC + cq)) * HW + (size_t)h * WW + gc;
                const float x0 = feat_r[base];
                const float x1 = feat_r[base + HW];
                const float x2 = feat_r[base + 2 * HW];
                const float x3 = feat_r[base + 3 * HW];
                float4 v;
                v.x = inr ? x0 : 0.0f;
                v.y = inr ? x1 : 0.0f;
                v.z = inr ? x2 : 0.0f;
                v.w = inr ? x3 : 0.0f;
                *(float4*)&smem[col * SC + cq] = v;
            }
        }
    }
    __syncthreads();

    // ---- per-pixel interp setup (shared across all di) ----
    const float pxf = (float)w - d;
    const float x0f = floorf(pxf);
    const float w1  = pxf - x0f;          // right-neighbor weight
    const float w0  = 1.0f - w1;
    int lb = (int)x0f - COL0 - 11;        // local col of tap j=0
    lb = min(max(lb, 0), NCOLS - 24);     // no-op for disp in [0,64)

    // ---- 24-tap window, prefetch distance 2, 8 channels per thread ----
    float4 Ta[3], Tb[3];
    #define LOADTAP(idx, j) { \
        const float4* p_ = (const float4*)&smem[(lb + (j)) * SC + c0]; \
        Ta[idx] = p_[0]; Tb[idx] = p_[1]; }

    LOADTAP(0, 0)
    LOADTAP(1, 1)

    float acc[DD];
    #pragma unroll
    for (int di = 0; di < DD; ++di) {
        if (di + 2 < 24) LOADTAP((di + 2) % 3, di + 2)
        const float4 A0 = Ta[di % 3],       A1 = Tb[di % 3];
        const float4 B0 = Ta[(di + 1) % 3], B1 = Tb[(di + 1) % 3];
        float sA = 0.0f, sB = 0.0f;
        sA += fabsf(fmaf(w0, A0.x, fmaf(w1, B0.x, -fl[0])));
        sB += fabsf(fmaf(w0, A0.y, fmaf(w1, B0.y, -fl[1])));
        sA += fabsf(fmaf(w0, A0.z, fmaf(w1, B0.z, -fl[2])));
        sB += fabsf(fmaf(w0, A0.w, fmaf(w1, B0.w, -fl[3])));
        sA += fabsf(fmaf(w0, A1.x, fmaf(w1, B1.x, -fl[4])));
        sB += fabsf(fmaf(w0, A1.y, fmaf(w1, B1.y, -fl[5])));
        sA += fabsf(fmaf(w0, A1.z, fmaf(w1, B1.z, -fl[6])));
        sB += fabsf(fmaf(w0, A1.w, fmaf(w1, B1.w, -fl[7])));
        acc[di] = sA + sB;
    }
    #undef LOADTAP

    // ---- cross-wave channel combine (reuse smem; stride 23 = conflict-free) ----
    __syncthreads();                       // all tap reads done before overwrite
    if (q != 0) {
        float* r = &smem[(q - 1) * (64 * RED) + px * RED];
        #pragma unroll
        for (int di = 0; di < DD; ++di) r[di] = acc[di];
    }
    __syncthreads();
    if (q == 0) {
        const float* r0 = &smem[0 * (64 * RED) + px * RED];
        const float* r1 = &smem[1 * (64 * RED) + px * RED];
        const float* r2 = &smem[2 * (64 * RED) + px * RED];
        #pragma unroll
        for (int di = 0; di < DD; ++di) {
            const float v = acc[di] + r0[di] + r1[di] + r2[di];
            out[((size_t)(b * DD + di)) * HW + (size_t)h * WW + w] = v;
        }
    }
}

extern "C" void kernel_launch(void* const* d_in, const int* in_sizes, int n_in,
                              void* d_out, int out_size, void* d_ws, size_t ws_size,
                              hipStream_t stream)
{
    const float* feat_l = (const float*)d_in[0];
    const float* feat_r = (const float*)d_in[1];
    const float* disp   = (const float*)d_in[2];
    float* out = (float*)d_out;

    dim3 grid(NSEG * BB * HH);   // 1024 blocks: (wseg, b, h); 4 blocks/CU
    dim3 block(256);             // 4 waves: one channel-octet each
    cost_volume_kernel<<<grid, block, 0, stream>>>(feat_l, feat_r, disp, out);
}

// Round 7
// 77.669 us; speedup vs baseline: 1.8842x; 1.0120x over previous
//
#include <hip/hip_runtime.h>

// Problem constants: B=2, C=32, H=128, W=256, maxdisp=12 -> D=23, shift = di-11
#define BB 2
#define CC 32
#define HH 128
#define WW 256
#define DD 23
#define HW (HH * WW)

#define SEG 64            // pixels per block (W split 4 ways)
#define NSEG 4
#define NCOLS 151         // staged cols: [64s-75 .. 64s+75]
#define SC 36             // col stride in dwords (144 B, 16B-aligned)
#define SLAB (64 * DD)    // 1472 floats per combine slab (stride 23, coprime 32)
#define SMEMN 5888        // max(151*36 = 5436 staging, 4*1472 = 5888 slabs)

// R6 established: R3 structure is the fast baseline (bench 78.6). This round's
// SINGLE change: 512-thread blocks (8 waves x 4 channels) instead of 256x8ch,
// doubling occupancy 16 -> 32 waves/CU to fight cold-cache/drain latency.
// (Harness re-poisons 268 MB before every launch -> L2+L3 swept cold.)

__global__ __launch_bounds__(512, 8) void cost_volume_kernel(
    const float* __restrict__ feat_l,
    const float* __restrict__ feat_r,
    const float* __restrict__ disp,
    float* __restrict__ out)
{
    __shared__ __align__(16) float smem[SMEMN];   // 23552 B -> 4 blocks/CU

    const int t  = threadIdx.x;
    const int q  = t >> 6;          // wave id 0..7, channel quad c0 = 4q
    const int px = t & 63;          // pixel within segment
    const int s  = blockIdx.x >> 8; // grid = NSEG*256; siblings same XCD (256%8==0)
    const int bh = blockIdx.x & 255;
    const int b  = bh >> 7;
    const int h  = bh & 127;
    const int w  = s * SEG + px;
    const int COL0 = s * SEG - 75;
    const int c0 = q * 4;

    // ---- early independent global loads (R3 order: feat_l first) ----
    float fl[4];
    const size_t lbase = ((size_t)(b * CC + c0)) * HW + (size_t)h * WW + w;
    #pragma unroll
    for (int k = 0; k < 4; ++k) fl[k] = feat_l[lbase + (size_t)k * HW];
    const float d = disp[(size_t)bh * WW + w];

    // ---- stage feat_r window: each thread loads its own quad at 3 cols ----
    #pragma unroll
    for (int cc = 0; cc < 3; ++cc) {
        const int col = cc * 64 + px;
        if (col < NCOLS) {
            const int  gcol = col + COL0;
            const bool inr  = (gcol >= 0) && (gcol < WW);
            const int  gc   = min(max(gcol, 0), WW - 1);   // safe address
            const size_t base = ((size_t)(b * CC + c0)) * HW + (size_t)h * WW + gc;
            const float x0 = feat_r[base];
            const float x1 = feat_r[base + HW];
            const float x2 = feat_r[base + 2 * HW];
            const float x3 = feat_r[base + 3 * HW];
            float4 v;
            v.x = inr ? x0 : 0.0f;
            v.y = inr ? x1 : 0.0f;
            v.z = inr ? x2 : 0.0f;
            v.w = inr ? x3 : 0.0f;
            *(float4*)&smem[col * SC + c0] = v;
        }
    }
    __syncthreads();

    // ---- per-pixel interp setup (shared across all di) ----
    const float pxf = (float)w - d;
    const float x0f = floorf(pxf);
    const float w1  = pxf - x0f;          // right-neighbor weight
    const float w0  = 1.0f - w1;
    int lb = (int)x0f - COL0 - 11;        // local col of tap j=0
    lb = min(max(lb, 0), NCOLS - 24);     // no-op for disp in [0,64)

    // ---- 24-tap window, prefetch distance 2, 4 channels per thread ----
    float4 T[3];
    #define LOADTAP(idx, j) \
        T[idx] = *(const float4*)&smem[(lb + (j)) * SC + c0];

    LOADTAP(0, 0)
    LOADTAP(1, 1)

    float acc[DD];
    #pragma unroll
    for (int di = 0; di < DD; ++di) {
        if (di + 2 < 24) LOADTAP((di + 2) % 3, di + 2)
        const float4 A = T[di % 3];
        const float4 Bv = T[(di + 1) % 3];
        float sA, sB;
        sA  = fabsf(fmaf(w0, A.x, fmaf(w1, Bv.x, -fl[0])));
        sB  = fabsf(fmaf(w0, A.y, fmaf(w1, Bv.y, -fl[1])));
        sA += fabsf(fmaf(w0, A.z, fmaf(w1, Bv.z, -fl[2])));
        sB += fabsf(fmaf(w0, A.w, fmaf(w1, Bv.w, -fl[3])));
        acc[di] = sA + sB;
    }
    #undef LOADTAP

    // ---- 2-stage tree combine across 8 waves (slab stride 23: conflict-free) ----
    __syncthreads();                       // all tap reads done before overwrite
    if (q >= 4) {                          // stage 1: waves 4..7 -> slabs 0..3
        float* r = &smem[(q - 4) * SLAB + px * DD];
        #pragma unroll
        for (int di = 0; di < DD; ++di) r[di] = acc[di];
    }
    __syncthreads();
    if (q < 4) {
        const float* r = &smem[q * SLAB + px * DD];
        #pragma unroll
        for (int di = 0; di < DD; ++di) acc[di] += r[di];
    }
    __syncthreads();                       // slab reads done before overwrite
    if (q >= 1 && q < 4) {                 // stage 2: waves 1..3 -> slabs 0..2
        float* r = &smem[(q - 1) * SLAB + px * DD];
        #pragma unroll
        for (int di = 0; di < DD; ++di) r[di] = acc[di];
    }
    __syncthreads();
    if (q == 0) {
        const float* r0 = &smem[0 * SLAB + px * DD];
        const float* r1 = &smem[1 * SLAB + px * DD];
        const float* r2 = &smem[2 * SLAB + px * DD];
        #pragma unroll
        for (int di = 0; di < DD; ++di) {
            const float v = acc[di] + r0[di] + r1[di] + r2[di];
            out[((size_t)(b * DD + di)) * HW + (size_t)h * WW + w] = v;
        }
    }
}

extern "C" void kernel_launch(void* const* d_in, const int* in_sizes, int n_in,
                              void* d_out, int out_size, void* d_ws, size_t ws_size,
                              hipStream_t stream)
{
    const float* feat_l = (const float*)d_in[0];
    const float* feat_r = (const float*)d_in[1];
    const float* disp   = (const float*)d_in[2];
    float* out = (float*)d_out;

    dim3 grid(NSEG * BB * HH);   // 1024 blocks: (wseg, b, h); 4 blocks/CU
    dim3 block(512);             // 8 waves: one channel-quad each
    cost_volume_kernel<<<grid, block, 0, stream>>>(feat_l, feat_r, disp, out);
}